// Round 3
// baseline (27111.249 us; speedup 1.0000x reference)
//
#include <hip/hip_runtime.h>
#include <math.h>

// ---------------- model constants ----------------
// HD=256 NL=4 NH=8 DH=32 MP=8 MS=32 T=40 ES=64 BATCH=8 BEAMS=5 BB=40
// START=1 END=2 MIN_LL_PEN=-100000
// Prefill (ti=0): beams within a batch are identical -> compute 8 batches x 9 rows = 72 rows,
// store K/V in the batch-leader beam slot (b*5) and point ptr ancestry at the leader.

// ---------------- reductions ----------------
__device__ __forceinline__ float blockSum1024(float v, float* red) {
#pragma unroll
  for (int off = 32; off >= 1; off >>= 1) v += __shfl_xor(v, off);
  __syncthreads();
  if ((threadIdx.x & 63) == 0) red[threadIdx.x >> 6] = v;
  __syncthreads();
  float s = 0.f;
#pragma unroll
  for (int i = 0; i < 16; ++i) s += red[i];
  return s;
}

// ---------------- conv kernels ----------------
// conv1 (IC=1): unchanged generic kernel
template <int IC, int OC, int OD, int CHUNKS>
__global__ __launch_bounds__(256) void conv_v1(const float* __restrict__ in,
                                               const float* __restrict__ w,
                                               const float* __restrict__ bias,
                                               float* __restrict__ out) {
  constexpr int ID = OD * 2;
  constexpr int ID2 = ID * ID;
  __shared__ float wl[IC * 64];
  int bi = blockIdx.x;
  int chunk = bi % CHUNKS;
  int oc = (bi / CHUNKS) % OC;
  int b = bi / (CHUNKS * OC);
  for (int i = threadIdx.x; i < IC * 64; i += 256) wl[i] = w[oc * IC * 64 + i];
  __syncthreads();
  int s = chunk * 256 + threadIdx.x;
  if (s >= OD * OD * OD) return;
  int od = s / (OD * OD), oh = (s / OD) % OD, ow = s % OD;
  float acc = 0.f;
  for (int ic = 0; ic < IC; ++ic) {
    const float* ipb = in + (size_t)(b * IC + ic) * (ID * ID2);
    const float* wp = wl + ic * 64;
#pragma unroll
    for (int kd = 0; kd < 4; ++kd) {
      int id = od * 2 - 1 + kd;
      if ((unsigned)id < (unsigned)ID) {
#pragma unroll
        for (int kh = 0; kh < 4; ++kh) {
          int ih = oh * 2 - 1 + kh;
          if ((unsigned)ih < (unsigned)ID) {
            const float* rowp = ipb + id * ID2 + ih * ID;
#pragma unroll
            for (int kw = 0; kw < 4; ++kw) {
              int iw = ow * 2 - 1 + kw;
              if ((unsigned)iw < (unsigned)ID)
                acc = fmaf(rowp[iw], wp[kd * 16 + kh * 4 + kw], acc);
            }
          }
        }
      }
    }
  }
  acc += bias[oc];
  out[((size_t)(b * OC + oc) * OD + od) * (OD * OD) + oh * OD + ow] = fmaxf(acc, 0.f);
}

// conv2: IC=32 OC=64 ID=32 OD=16. LDS-staged padded patch + weight group, dbuf.
// grid = b(8) x od(16) x ocg(8); block 256 = 16x16 (oh,ow); OCG=8.
__global__ __launch_bounds__(256) void conv_t2(const float* __restrict__ in,
                                               const float* __restrict__ w,
                                               const float* __restrict__ bias,
                                               float* __restrict__ out) {
  __shared__ float patch[2][4864];  // 4*34*34 = 4624, padded to 19*256
  __shared__ float wl[2][512];
  const int bi = blockIdx.x;
  const int od = bi & 15;
  const int ocg = (bi >> 4) & 7;
  const int b = bi >> 7;
  const int t = threadIdx.x;
  const int oh = t >> 4, ow = t & 15;

  // precompute patch gather offsets (ic=0 base), -1 = zero-pad
  int off[19];
#pragma unroll
  for (int n = 0; n < 19; ++n) {
    int idx = t + n * 256;
    off[n] = -1;
    if (idx < 4624) {
      int kd = idx / 1156;
      int r = idx - kd * 1156;
      int py = r / 34, px = r - py * 34;
      int id = od * 2 - 1 + kd;
      int ih = py - 1, iw = px - 1;
      if ((unsigned)id < 32u && (unsigned)ih < 32u && (unsigned)iw < 32u)
        off[n] = (b * 32) * 32768 + id * 1024 + ih * 32 + iw;
    }
  }
  const int wbase = (ocg * 8 + (t >> 6)) * 32 * 64 + (t & 63);
  const int wbase2 = (ocg * 8 + ((t + 256) >> 6)) * 32 * 64 + (t & 63);
  // stage ic=0
#pragma unroll
  for (int n = 0; n < 19; ++n) patch[0][t + n * 256] = (off[n] >= 0) ? in[off[n]] : 0.f;
  wl[0][t] = w[wbase];
  wl[0][t + 256] = w[wbase2];
  __syncthreads();

  float acc[8];
#pragma unroll
  for (int o = 0; o < 8; ++o) acc[o] = 0.f;

  for (int ic = 0; ic < 32; ++ic) {
    const int buf = ic & 1;
    float rv[19], wr0 = 0.f, wr1 = 0.f;
    if (ic < 31) {
#pragma unroll
      for (int n = 0; n < 19; ++n)
        rv[n] = (off[n] >= 0) ? in[off[n] + (ic + 1) * 32768] : 0.f;
      wr0 = w[wbase + (ic + 1) * 64];
      wr1 = w[wbase2 + (ic + 1) * 64];
    }
    const float* pb = &patch[buf][0];
    const float* wb = &wl[buf][0];
#pragma unroll
    for (int kd = 0; kd < 4; ++kd)
#pragma unroll
      for (int kh = 0; kh < 4; ++kh) {
        const float* prow = pb + kd * 1156 + (oh * 2 + kh) * 34 + ow * 2;
#pragma unroll
        for (int kw = 0; kw < 4; ++kw) {
          float iv = prow[kw];
          int tap = kd * 16 + kh * 4 + kw;
#pragma unroll
          for (int o = 0; o < 8; ++o) acc[o] = fmaf(iv, wb[o * 64 + tap], acc[o]);
        }
      }
    __syncthreads();
    if (ic < 31) {
#pragma unroll
      for (int n = 0; n < 19; ++n) patch[buf ^ 1][t + n * 256] = rv[n];
      wl[buf ^ 1][t] = wr0;
      wl[buf ^ 1][t + 256] = wr1;
    }
    __syncthreads();
  }
#pragma unroll
  for (int o = 0; o < 8; ++o) {
    int oc = ocg * 8 + o;
    out[(((size_t)(b * 64 + oc) * 16 + od) * 16 + oh) * 16 + ow] =
        fmaxf(acc[o] + bias[oc], 0.f);
  }
}

// conv3: IC=64 OC=128 ID=16 OD=8. grid = b(8) x odg(2) x ocg(32); block 256 = 4 od x 8x8; OCG=4.
__global__ __launch_bounds__(256) void conv_t3(const float* __restrict__ in,
                                               const float* __restrict__ w,
                                               const float* __restrict__ bias,
                                               float* __restrict__ out) {
  __shared__ float patch[2][3328];  // 10*18*18 = 3240, padded to 13*256
  __shared__ float wl[2][256];
  const int bi = blockIdx.x;
  const int ocg = bi & 31;
  const int odg = (bi >> 5) & 1;
  const int b = bi >> 6;
  const int t = threadIdx.x;
  const int od_l = t >> 6;
  const int oh = (t >> 3) & 7, ow = t & 7;

  int off[13];
#pragma unroll
  for (int n = 0; n < 13; ++n) {
    int idx = t + n * 256;
    off[n] = -1;
    if (idx < 3240) {
      int s = idx / 324;
      int r = idx - s * 324;
      int py = r / 18, px = r - py * 18;
      int id = odg * 8 - 1 + s;
      int ih = py - 1, iw = px - 1;
      if ((unsigned)id < 16u && (unsigned)ih < 16u && (unsigned)iw < 16u)
        off[n] = (b * 64) * 4096 + id * 256 + ih * 16 + iw;
    }
  }
  const int wbase = (ocg * 4 + (t >> 6)) * 64 * 64 + (t & 63);
#pragma unroll
  for (int n = 0; n < 13; ++n) patch[0][t + n * 256] = (off[n] >= 0) ? in[off[n]] : 0.f;
  wl[0][t] = w[wbase];
  __syncthreads();

  float acc[4];
#pragma unroll
  for (int o = 0; o < 4; ++o) acc[o] = 0.f;

  for (int ic = 0; ic < 64; ++ic) {
    const int buf = ic & 1;
    float rv[13], wr0 = 0.f;
    if (ic < 63) {
#pragma unroll
      for (int n = 0; n < 13; ++n)
        rv[n] = (off[n] >= 0) ? in[off[n] + (ic + 1) * 4096] : 0.f;
      wr0 = w[wbase + (ic + 1) * 64];
    }
    const float* pb = &patch[buf][0];
    const float* wb = &wl[buf][0];
#pragma unroll
    for (int kd = 0; kd < 4; ++kd) {
      int s = od_l * 2 + kd;
#pragma unroll
      for (int kh = 0; kh < 4; ++kh) {
        const float* prow = pb + s * 324 + (oh * 2 + kh) * 18 + ow * 2;
#pragma unroll
        for (int kw = 0; kw < 4; ++kw) {
          float iv = prow[kw];
          int tap = kd * 16 + kh * 4 + kw;
#pragma unroll
          for (int o = 0; o < 4; ++o) acc[o] = fmaf(iv, wb[o * 64 + tap], acc[o]);
        }
      }
    }
    __syncthreads();
    if (ic < 63) {
#pragma unroll
      for (int n = 0; n < 13; ++n) patch[buf ^ 1][t + n * 256] = rv[n];
      wl[buf ^ 1][t] = wr0;
    }
    __syncthreads();
  }
  int od = odg * 4 + od_l;
#pragma unroll
  for (int o = 0; o < 4; ++o) {
    int oc = ocg * 4 + o;
    out[(((size_t)(b * 128 + oc) * 8 + od) * 8 + oh) * 8 + ow] =
        fmaxf(acc[o] + bias[oc], 0.f);
  }
}

// conv4: unchanged
__global__ __launch_bounds__(64) void conv_v2(const float* __restrict__ in,
                                              const float* __restrict__ w,
                                              const float* __restrict__ bias,
                                              float* __restrict__ out) {
  constexpr int IC = 128, OD = 4, ID = 8, ID2 = 64;
  __shared__ float wl[IC * 64];
  int oc = blockIdx.x % 256;
  int b = blockIdx.x / 256;
  for (int i = threadIdx.x; i < IC * 64; i += 64) wl[i] = w[oc * IC * 64 + i];
  __syncthreads();
  int s = threadIdx.x;
  int od = s >> 4, oh = (s >> 2) & 3, ow = s & 3;
  float acc = 0.f;
  for (int ic = 0; ic < IC; ++ic) {
    const float* ipb = in + (size_t)(b * IC + ic) * (ID * ID2);
    const float* wp = wl + ic * 64;
#pragma unroll
    for (int kd = 0; kd < 4; ++kd) {
      int id = od * 2 - 1 + kd;
      if ((unsigned)id < (unsigned)ID) {
#pragma unroll
        for (int kh = 0; kh < 4; ++kh) {
          int ih = oh * 2 - 1 + kh;
          if ((unsigned)ih < (unsigned)ID) {
            const float* rowp = ipb + id * ID2 + ih * ID;
#pragma unroll
            for (int kw = 0; kw < 4; ++kw) {
              int iw = ow * 2 - 1 + kw;
              if ((unsigned)iw < (unsigned)ID)
                acc = fmaf(rowp[iw], wp[kd * 16 + kh * 4 + kw], acc);
            }
          }
        }
      }
    }
  }
  acc += bias[oc];
  out[((size_t)(b * 256 + oc) * OD + od) * 16 + oh * 4 + ow] = fmaxf(acc, 0.f);
}

// conv5: unchanged (writes codes layout)
__global__ __launch_bounds__(256) void conv_v3(const float* __restrict__ in,
                                               const float* __restrict__ w,
                                               const float* __restrict__ bias,
                                               float* __restrict__ codes) {
  __shared__ float inl[256 * 64];
  int b = blockIdx.x >> 3;
  int ocg = blockIdx.x & 7;
  for (int i = threadIdx.x; i < 256 * 64; i += 256) inl[i] = in[b * 256 * 64 + i];
  __syncthreads();
  int oc = ocg * 32 + (threadIdx.x >> 3);
  int s = threadIdx.x & 7;
  int od = s >> 2, oh = (s >> 1) & 1, ow = s & 1;
  const float* wp = w + (size_t)oc * 256 * 64;
  float acc = 0.f;
  for (int ic = 0; ic < 256; ++ic) {
    const float* ib = inl + ic * 64;
    const float* wb = wp + ic * 64;
#pragma unroll
    for (int kd = 0; kd < 4; ++kd) {
      int id = od * 2 - 1 + kd;
      if ((unsigned)id < 4u) {
#pragma unroll
        for (int kh = 0; kh < 4; ++kh) {
          int ih = oh * 2 - 1 + kh;
          if ((unsigned)ih < 4u) {
#pragma unroll
            for (int kw = 0; kw < 4; ++kw) {
              int iw = ow * 2 - 1 + kw;
              if ((unsigned)iw < 4u)
                acc = fmaf(ib[id * 16 + ih * 4 + iw], wb[kd * 16 + kh * 4 + kw], acc);
            }
          }
        }
      }
    }
  }
  acc += bias[oc];
  codes[(b * 8 + s) * 256 + oc] = fmaxf(acc, 0.f);
}

// ---------------- decode: init (x for 72 prefill rows + state) ----------------
__global__ __launch_bounds__(256) void k_init(const float* __restrict__ codes,
                                              const float* __restrict__ tok_emb,
                                              const float* __restrict__ pos_emb,
                                              float* __restrict__ x,
                                              int* __restrict__ bseqs,
                                              float* __restrict__ blls,
                                              int* __restrict__ ptr) {
  int i = blockIdx.x;  // 0..71
  int c = threadIdx.x;
  int b = i / 9, ri = i - b * 9;
  float v = (ri < 8) ? codes[(b * 8 + ri) * 256 + c] : tok_emb[256 + c];  // START=1
  x[i * 256 + c] = v + pos_emb[ri * 256 + c];
  if (i == 0) {
    for (int t = c; t < 1280; t += 256) bseqs[t] = ((t & 31) == 0) ? 1 : 0;
    if (c < 40) blls[c] = (c % 5 == 0) ? 0.f : -100000.0f;
    for (int t = c; t < 1600; t += 256) ptr[t] = ((t / 40) / 5) * 5;  // leader
  }
}

// ---------------- phase A: LN1 + QKV GEMM (weights shared across beams) -------
// grid 12 WGs x 64 cols of 768; block 512 = 64 cols x 8 rowgroups.
template <int PRE, int CH>
__device__ __forceinline__ void qkv_chunk(int base, int ti, int l, const float* x,
                                          const float* Wl, const float* ln1s,
                                          const float* ln1b, float* q, float* Kc,
                                          float* Vc, float (*hs)[256], int c) {
  const int t = threadIdx.x;
  const int lane = t & 63;
  const int rg = t >> 6;  // 0..7 (wave-aligned)
  // stage + LN
  for (int r = rg; r < CH; r += 8) {
    const float4 xv = *(const float4*)(x + (size_t)(base + r) * 256 + lane * 4);
    float s = xv.x + xv.y + xv.z + xv.w;
#pragma unroll
    for (int off = 32; off >= 1; off >>= 1) s += __shfl_xor(s, off);
    float mean = s * (1.f / 256.f);
    float dx = xv.x - mean, dy = xv.y - mean, dz = xv.z - mean, dw = xv.w - mean;
    float v = dx * dx + dy * dy + dz * dz + dw * dw;
#pragma unroll
    for (int off = 32; off >= 1; off >>= 1) v += __shfl_xor(v, off);
    float rsd = 1.f / sqrtf(v * (1.f / 256.f) + 1e-5f);
    int cb = l * 256 + lane * 4;
    hs[r][lane * 4 + 0] = dx * rsd * ln1s[cb + 0] + ln1b[cb + 0];
    hs[r][lane * 4 + 1] = dy * rsd * ln1s[cb + 1] + ln1b[cb + 1];
    hs[r][lane * 4 + 2] = dz * rsd * ln1s[cb + 2] + ln1b[cb + 2];
    hs[r][lane * 4 + 3] = dw * rsd * ln1s[cb + 3] + ln1b[cb + 3];
  }
  __syncthreads();
  float acc[CH / 8];
#pragma unroll
  for (int rr = 0; rr < CH / 8; ++rr) acc[rr] = 0.f;
  for (int k = 0; k < 256; k += 4) {
    float w0 = Wl[(k + 0) * 768 + c];
    float w1 = Wl[(k + 1) * 768 + c];
    float w2 = Wl[(k + 2) * 768 + c];
    float w3 = Wl[(k + 3) * 768 + c];
#pragma unroll
    for (int rr = 0; rr < CH / 8; ++rr) {
      const float4 hv = *(const float4*)&hs[rg + rr * 8][k];
      acc[rr] = fmaf(hv.x, w0, fmaf(hv.y, w1, fmaf(hv.z, w2, fmaf(hv.w, w3, acc[rr]))));
    }
  }
#pragma unroll
  for (int rr = 0; rr < CH / 8; ++rr) {
    int i = base + rg + rr * 8;
    int slot, row;
    if (PRE) {
      int b = i / 9;
      slot = b * 5;
      row = i - b * 9;
    } else {
      slot = i;
      row = 8 + ti;
    }
    float val = acc[rr];
    if (c < 256)
      q[i * 256 + c] = val;
    else if (c < 512)
      Kc[(((size_t)l * 40 + slot) * 40 + row) * 256 + (c - 256)] = val;
    else
      Vc[(((size_t)l * 40 + slot) * 40 + row) * 256 + (c - 512)] = val;
  }
  __syncthreads();
}

template <int PRE>
__global__ __launch_bounds__(512) void k_qkv(int ti, int l, const float* __restrict__ x,
                                             const float* __restrict__ Wqkv,
                                             const float* __restrict__ ln1s,
                                             const float* __restrict__ ln1b,
                                             float* __restrict__ q, float* __restrict__ Kc,
                                             float* __restrict__ Vc) {
  __shared__ float hs[40][256];
  const int c = blockIdx.x * 64 + (threadIdx.x & 63);
  const float* Wl = Wqkv + (size_t)l * 196608;
  qkv_chunk<PRE, 40>(0, ti, l, x, Wl, ln1s, ln1b, q, Kc, Vc, hs, c);
  if (PRE) qkv_chunk<PRE, 32>(40, ti, l, x, Wl, ln1s, ln1b, q, Kc, Vc, hs, c);
}

// ---------------- phase B: attention + Wo + residual + LN2 (per row-job) ------
template <int PRE>
__global__ __launch_bounds__(1024) void k_attn(int ti, int l, float* __restrict__ x,
                                               const float* __restrict__ q,
                                               const float* __restrict__ Kc,
                                               const float* __restrict__ Vc,
                                               const int* __restrict__ ptr,
                                               const float* __restrict__ Wo,
                                               const float* __restrict__ ln2s,
                                               const float* __restrict__ ln2b,
                                               float* __restrict__ h2) {
  const int i = blockIdx.x;
  int slot, row;
  if (PRE) {
    int b = i / 9;
    slot = b * 5;
    row = i - b * 9;
  } else {
    slot = i;
    row = 8 + ti;
  }
  const int tid = threadIdx.x;
  const int col = tid & 255;
  const int ks = tid >> 8;
  __shared__ float qs[256], aos[256], xsh[256];
  __shared__ float pbuf[4][256];
  __shared__ float scs[8][48];
  __shared__ float red[16];
  __shared__ int ips[40];
  if (tid < 40) ips[tid] = ptr[slot * 40 + tid];
  if (tid < 256) qs[tid] = q[(size_t)i * 256 + tid];
  __syncthreads();
  {
    int h = tid >> 7, j = tid & 127;
    if (j <= row) {
      const float* kp = Kc + (((size_t)l * 40 + ips[j]) * 40 + j) * 256 + h * 32;
      float s = 0.f;
#pragma unroll
      for (int dd = 0; dd < 32; ++dd) s = fmaf(qs[h * 32 + dd], kp[dd], s);
      scs[h][j] = s * 0.17677669529663687f;
    }
  }
  __syncthreads();
  {
    int hh = col >> 5;
    float m = -3.4e38f;
    for (int jj = 0; jj <= row; ++jj) m = fmaxf(m, scs[hh][jj]);
    float sum = 0.f;
    for (int jj = 0; jj <= row; ++jj) sum += expf(scs[hh][jj] - m);
    float o = 0.f;
    for (int jj = ks; jj <= row; jj += 4) {
      float p = expf(scs[hh][jj] - m) / sum;
      o = fmaf(p, Vc[(((size_t)l * 40 + ips[jj]) * 40 + jj) * 256 + col], o);
    }
    pbuf[ks][col] = o;
  }
  __syncthreads();
  if (tid < 256) aos[tid] = pbuf[0][tid] + pbuf[1][tid] + pbuf[2][tid] + pbuf[3][tid];
  __syncthreads();
  {
    const float* wb = Wo + (size_t)l * 65536 + (size_t)(ks * 64) * 256;
    float a = 0.f;
#pragma unroll 8
    for (int k = 0; k < 64; ++k) a = fmaf(aos[ks * 64 + k], wb[k * 256 + col], a);
    pbuf[ks][col] = a;
  }
  __syncthreads();
  if (tid < 256) {
    float xv = x[(size_t)i * 256 + tid] + pbuf[0][tid] + pbuf[1][tid] + pbuf[2][tid] +
               pbuf[3][tid];
    x[(size_t)i * 256 + tid] = xv;
    xsh[tid] = xv;
  }
  __syncthreads();
  float xv = xsh[col];
  float mean = blockSum1024(xv, red) * (1.f / 1024.f);
  float dv = xv - mean;
  float var = blockSum1024(dv * dv, red) * (1.f / 1024.f);
  float rsd = 1.f / sqrtf(var + 1e-5f);
  if (ks == 0) h2[(size_t)i * 256 + col] = dv * rsd * ln2s[l * 256 + col] + ln2b[l * 256 + col];
}

// ---------------- phase C: FF1 GEMM (shared weights) ---------------------------
template <int PRE, int CH>
__device__ __forceinline__ void ff1_chunk(int base, int l, const float* h2,
                                          const float* Wl, const float* bff1, float* f1,
                                          float (*hs)[256], int c) {
  const int t = threadIdx.x;
  const int lane = t & 63;
  const int rg = t >> 6;
  for (int r = rg; r < CH; r += 8) {
    *(float4*)&hs[r][lane * 4] = *(const float4*)(h2 + (size_t)(base + r) * 256 + lane * 4);
  }
  __syncthreads();
  float acc[CH / 8];
#pragma unroll
  for (int rr = 0; rr < CH / 8; ++rr) acc[rr] = 0.f;
  for (int k = 0; k < 256; k += 4) {
    float w0 = Wl[(k + 0) * 1024 + c];
    float w1 = Wl[(k + 1) * 1024 + c];
    float w2 = Wl[(k + 2) * 1024 + c];
    float w3 = Wl[(k + 3) * 1024 + c];
#pragma unroll
    for (int rr = 0; rr < CH / 8; ++rr) {
      const float4 hv = *(const float4*)&hs[rg + rr * 8][k];
      acc[rr] = fmaf(hv.x, w0, fmaf(hv.y, w1, fmaf(hv.z, w2, fmaf(hv.w, w3, acc[rr]))));
    }
  }
  float bv = bff1[l * 1024 + c];
#pragma unroll
  for (int rr = 0; rr < CH / 8; ++rr) {
    int i = base + rg + rr * 8;
    f1[(size_t)i * 1024 + c] = fmaxf(acc[rr] + bv, 0.f);
  }
  __syncthreads();
}

template <int PRE>
__global__ __launch_bounds__(512) void k_ff1(int l, const float* __restrict__ h2,
                                             const float* __restrict__ Wff1,
                                             const float* __restrict__ bff1,
                                             float* __restrict__ f1) {
  __shared__ float hs[40][256];
  const int c = blockIdx.x * 64 + (threadIdx.x & 63);
  const float* Wl = Wff1 + (size_t)l * 262144;
  ff1_chunk<PRE, 40>(0, l, h2, Wl, bff1, f1, hs, c);
  if (PRE) ff1_chunk<PRE, 32>(40, l, h2, Wl, bff1, f1, hs, c);
}

// ---------------- phase D: FF2 GEMM + residual ---------------------------------
// grid 64 WGs x 4 cols; block 256 = 4 cols x 64 rowgroups; k=1024.
template <int PRE>
__global__ __launch_bounds__(256) void k_ff2(int l, const float* __restrict__ f1,
                                             const float* __restrict__ Wff2,
                                             const float* __restrict__ bff2,
                                             float* __restrict__ x) {
  const int M = PRE ? 72 : 40;
  const int t = threadIdx.x;
  const int c = blockIdx.x * 4 + (t & 3);
  const int rg = t >> 2;  // 0..63
  const int i0 = rg, i1 = rg + 64;
  const bool v0 = i0 < M, v1 = i1 < M;
  const float* Wl = Wff2 + (size_t)l * 262144;
  float a0 = 0.f, a1 = 0.f;
  for (int k = 0; k < 1024; k += 4) {
    float w0 = Wl[(k + 0) * 256 + c];
    float w1 = Wl[(k + 1) * 256 + c];
    float w2 = Wl[(k + 2) * 256 + c];
    float w3 = Wl[(k + 3) * 256 + c];
    if (v0) {
      const float4 f = *(const float4*)(f1 + (size_t)i0 * 1024 + k);
      a0 = fmaf(f.x, w0, fmaf(f.y, w1, fmaf(f.z, w2, fmaf(f.w, w3, a0))));
    }
    if (v1) {
      const float4 f = *(const float4*)(f1 + (size_t)i1 * 1024 + k);
      a1 = fmaf(f.x, w0, fmaf(f.y, w1, fmaf(f.z, w2, fmaf(f.w, w3, a1))));
    }
  }
  float bv = bff2[l * 256 + c];
  if (v0) x[(size_t)i0 * 256 + c] = x[(size_t)i0 * 256 + c] + a0 + bv;
  if (v1) x[(size_t)i1 * 256 + c] = x[(size_t)i1 * 256 + c] + a1 + bv;
}

// ---------------- head ----------------------------------------------------------
template <int PRE>
__global__ __launch_bounds__(1024) void k_head(const float* __restrict__ x,
                                               const float* __restrict__ hW1,
                                               const float* __restrict__ hb1,
                                               const float* __restrict__ hW2,
                                               const float* __restrict__ hb2,
                                               float* __restrict__ logits) {
  const int bIdx = blockIdx.x;
  const int i = PRE ? (bIdx * 9 + 8) : bIdx;
  const int tid = threadIdx.x;
  const int col = tid & 255;
  const int ks = tid >> 8;
  __shared__ float xr[256], f1s[256];
  __shared__ float pb[4][256];
  __shared__ float pb2[1024];
  if (tid < 256) xr[tid] = x[(size_t)i * 256 + tid];
  __syncthreads();
  {
    const float* wb = hW1 + (size_t)(ks * 64) * 256;
    float a = 0.f;
#pragma unroll 8
    for (int k = 0; k < 64; ++k) a = fmaf(xr[ks * 64 + k], wb[k * 256 + col], a);
    pb[ks][col] = a;
  }
  __syncthreads();
  if (tid < 256)
    f1s[tid] = fmaxf(pb[0][tid] + pb[1][tid] + pb[2][tid] + pb[3][tid] + hb1[tid], 0.f);
  __syncthreads();
  {
    int ks2 = tid >> 6, c2 = tid & 63;
    const float* w2 = hW2 + (size_t)(ks2 * 16) * 64;
    float g = 0.f;
#pragma unroll
    for (int k = 0; k < 16; ++k) g = fmaf(f1s[ks2 * 16 + k], w2[k * 64 + c2], g);
    pb2[tid] = g;
  }
  __syncthreads();
  if (tid < 64) {
    float s = 0.f;
#pragma unroll
    for (int i2 = 0; i2 < 16; ++i2) s += pb2[i2 * 64 + tid];
    s += hb2[tid];
    if (PRE) {
#pragma unroll
      for (int bm = 0; bm < 5; ++bm) logits[(bIdx * 5 + bm) * 64 + tid] = s;
    } else {
      logits[bIdx * 64 + tid] = s;
    }
  }
}

// ---------------- beam update (exact tie semantics) + next-step embedding ------
__global__ __launch_bounds__(256) void k_beam(int ti, const float* __restrict__ logits,
                                              int* __restrict__ bseqs,
                                              float* __restrict__ blls,
                                              int* __restrict__ ptr,
                                              const float* __restrict__ tok_emb,
                                              const float* __restrict__ pos_emb,
                                              float* __restrict__ x) {
  __shared__ float lg[40][64];
  __shared__ float bdist[40][64];
  __shared__ float rm[40], rsum[40];
  __shared__ float bd[40][5];
  __shared__ int bc[40][5];
  __shared__ float oll[40], nll[40];
  __shared__ int nts[40], oldx[40];
  __shared__ int oseq[40][32];
  __shared__ int optr[40][40];
  int t = threadIdx.x;
  for (int i = t; i < 2560; i += 256) ((float*)lg)[i] = logits[i];
  for (int i = t; i < 1280; i += 256) ((int*)oseq)[i] = bseqs[i];
  for (int i = t; i < 1600; i += 256) ((int*)optr)[i] = ptr[i];
  if (t < 40) oll[t] = blls[t];
  __syncthreads();
  if (t < 40) {
    float m = -3.4e38f;
    for (int j = 0; j < 64; ++j) m = fmaxf(m, lg[t][j]);
    float s = 0.f;
    for (int j = 0; j < 64; ++j) s += expf(lg[t][j] - m);
    rm[t] = m;
    rsum[t] = s;
  }
  __syncthreads();
  for (int i = t; i < 2560; i += 256) {
    int r = i >> 6, j = i & 63;
    bdist[r][j] = logf(expf(lg[r][j] - rm[r]) / rsum[r] + 1e-8f);
  }
  __syncthreads();
  if (t < 40) {
    float pv = 3.4e38f;
    int pi = -1;
    for (int r = 0; r < 5; ++r) {
      float bv = -3.4e38f;
      int bi = -1;
      for (int j = 0; j < 64; ++j) {
        float v = bdist[t][j];
        bool lessprev = (v < pv) || (v == pv && j > pi);
        if (lessprev && v > bv) { bv = v; bi = j; }
      }
      bd[t][r] = bv; bc[t][r] = bi; pv = bv; pi = bi;
    }
  }
  __syncthreads();
  if (t < 8) {
    float pv = 3.4e38f;
    int pi = -1;
    for (int r = 0; r < 5; ++r) {
      float bv = -3.4e38f;
      int bi = -1;
      for (int idx = 0; idx < 25; ++idx) {
        int kb = idx / 5, j = idx % 5;
        float v = bd[t * 5 + kb][j] + oll[t * 5 + kb];
        bool lessprev = (v < pv) || (v == pv && idx > pi);
        if (lessprev && v > bv) { bv = v; bi = idx; }
      }
      int kb = bi / 5, j = bi % 5;
      int tok = bc[t * 5 + kb][j];
      int bbn = t * 5 + r;
      nts[bbn] = tok;
      oldx[bbn] = t * 5 + kb;
      nll[bbn] = (tok == 2) ? (bv - 100000.0f) : bv;
      pv = bv; pi = bi;
    }
  }
  __syncthreads();
  for (int i = t; i < 1280; i += 256) {
    int bb = i >> 5, j = i & 31;
    int v = oseq[oldx[bb]][j];
    if (j == ti + 1) v = nts[bb];
    bseqs[i] = v;
  }
  int r1 = 8 + ti;
  for (int i = t; i < 1600; i += 256) {
    int bb = i / 40, j = i % 40;
    ptr[i] = (j <= r1) ? optr[oldx[bb]][j] : bb;
  }
  if (t < 40) blls[t] = nll[t];
  // next-step embedding: x[bb] = tok_emb[nt] + pos_emb[9+ti]
  const float* pe = pos_emb + (9 + ti) * 256;
  for (int i = t; i < 40 * 256; i += 256) {
    int bb = i >> 8, c = i & 255;
    x[i] = tok_emb[nts[bb] * 256 + c] + pe[c];
  }
}

// ---------------- final output ----------------
__global__ void k_out(const int* __restrict__ bseqs, const float* __restrict__ blls,
                      float* __restrict__ out) {
  int t = blockIdx.x * 256 + threadIdx.x;
  if (t < 1280) out[t] = (float)bseqs[t];
  else if (t < 1320) out[t] = blls[t - 1280];
}

// ---------------- host ----------------
extern "C" void kernel_launch(void* const* d_in, const int* in_sizes, int n_in,
                              void* d_out, int out_size, void* d_ws, size_t ws_size,
                              hipStream_t stream) {
  const float* voxels = (const float*)d_in[0];
  const float* ck1 = (const float*)d_in[1];
  const float* cb1 = (const float*)d_in[2];
  const float* ck2 = (const float*)d_in[3];
  const float* cb2 = (const float*)d_in[4];
  const float* ck3 = (const float*)d_in[5];
  const float* cb3 = (const float*)d_in[6];
  const float* ck4 = (const float*)d_in[7];
  const float* cb4 = (const float*)d_in[8];
  const float* ck5 = (const float*)d_in[9];
  const float* cb5 = (const float*)d_in[10];
  const float* tok_emb = (const float*)d_in[11];
  const float* pos_emb = (const float*)d_in[12];
  const float* Wqkv = (const float*)d_in[13];
  const float* Wo = (const float*)d_in[14];
  const float* ln1s = (const float*)d_in[15];
  const float* ln1b = (const float*)d_in[16];
  const float* ln2s = (const float*)d_in[17];
  const float* ln2b = (const float*)d_in[18];
  const float* Wff1 = (const float*)d_in[19];
  const float* bff1 = (const float*)d_in[20];
  const float* Wff2 = (const float*)d_in[21];
  const float* bff2 = (const float*)d_in[22];
  const float* hW1 = (const float*)d_in[23];
  const float* hb1 = (const float*)d_in[24];
  const float* hW2 = (const float*)d_in[25];
  const float* hb2 = (const float*)d_in[26];

  float* ws = (float*)d_ws;
  // conv chain buffers
  float* c1 = ws;             // 8,388,608 f
  float* c2 = c1 + 8388608;   // 2,097,152 f
  float* c3 = c2 + 2097152;   //   524,288 f
  float* c4 = c3 + 524288;    //   131,072 f
  float* codes = c4 + 131072; //    16,384 f
  // decode region aliases c1 (conv1 output dead by then); codes lives beyond it.
  float* Kc = ws;                  // 1,638,400 f
  float* Vc = Kc + 1638400;        // 1,638,400 f
  float* qb = Vc + 1638400;        // 18,432 f
  float* h2 = qb + 18432;          // 18,432 f
  float* f1 = h2 + 18432;          // 73,728 f
  float* xb = f1 + 73728;          // 18,432 f
  float* logits = xb + 18432;      // 2,560 f
  float* blls = logits + 2560;     // 40 f
  int* bseqs = (int*)(blls + 40);  // 1,280 i
  int* ptr = bseqs + 1280;         // 1,600 i

  conv_v1<1, 32, 32, 128><<<8 * 32 * 128, 256, 0, stream>>>(voxels, ck1, cb1, c1);
  conv_t2<<<8 * 16 * 8, 256, 0, stream>>>(c1, ck2, cb2, c2);
  conv_t3<<<8 * 2 * 32, 256, 0, stream>>>(c2, ck3, cb3, c3);
  conv_v2<<<8 * 256, 64, 0, stream>>>(c3, ck4, cb4, c4);
  conv_v3<<<8 * 8, 256, 0, stream>>>(c4, ck5, cb5, codes);

  k_init<<<72, 256, 0, stream>>>(codes, tok_emb, pos_emb, xb, bseqs, blls, ptr);

  // ti = 0 (prefill, 72 distinct rows)
  for (int l = 0; l < 4; ++l) {
    k_qkv<1><<<12, 512, 0, stream>>>(0, l, xb, Wqkv, ln1s, ln1b, qb, Kc, Vc);
    k_attn<1><<<72, 1024, 0, stream>>>(0, l, xb, qb, Kc, Vc, ptr, Wo, ln2s, ln2b, h2);
    k_ff1<1><<<16, 512, 0, stream>>>(l, h2, Wff1, bff1, f1);
    k_ff2<1><<<64, 256, 0, stream>>>(l, f1, Wff2, bff2, xb);
  }
  k_head<1><<<8, 1024, 0, stream>>>(xb, hW1, hb1, hW2, hb2, logits);
  k_beam<<<1, 256, 0, stream>>>(0, logits, bseqs, blls, ptr, tok_emb, pos_emb, xb);

  for (int ti = 1; ti < 31; ++ti) {
    for (int l = 0; l < 4; ++l) {
      k_qkv<0><<<12, 512, 0, stream>>>(ti, l, xb, Wqkv, ln1s, ln1b, qb, Kc, Vc);
      k_attn<0><<<40, 1024, 0, stream>>>(ti, l, xb, qb, Kc, Vc, ptr, Wo, ln2s, ln2b, h2);
      k_ff1<0><<<16, 512, 0, stream>>>(l, h2, Wff1, bff1, f1);
      k_ff2<0><<<64, 256, 0, stream>>>(l, f1, Wff2, bff2, xb);
    }
    k_head<0><<<40, 1024, 0, stream>>>(xb, hW1, hb1, hW2, hb2, logits);
    k_beam<<<1, 256, 0, stream>>>(ti, logits, bseqs, blls, ptr, tok_emb, pos_emb, xb);
  }
  k_out<<<6, 256, 0, stream>>>(bseqs, blls, (float*)d_out);
}